// Round 18
// baseline (420.187 us; speedup 1.0000x reference)
//
#include <hip/hip_runtime.h>
#include <hip/hip_bf16.h>

#define B_  128
#define S_  512
#define H_  64
#define E_  64
#define G3  192   // 3*H
#define V_  4996
#define VCHUNK 32
#define CHUNK  8             // steps per LDS xw chunk
#define NCHUNK (S_ / CHUNK)  // 64
#define STOK  (S_ + CHUNK)   // scan-ordered tokens + one pad chunk
#define WPAD  68             // padded weight row stride (f32) -> BW-bound reads

typedef float f32x4 __attribute__((ext_vector_type(4)));

__device__ __forceinline__ float fast_rcp(float x) {
#if __has_builtin(__builtin_amdgcn_rcpf)
    return __builtin_amdgcn_rcpf(x);
#else
    return 1.0f / x;
#endif
}
__device__ __forceinline__ float fast_exp(float x) {   // e^x
#if __has_builtin(__builtin_amdgcn_exp2f)
    return __builtin_amdgcn_exp2f(x * 1.44269504f);
#else
    return __expf(x);
#endif
}
__device__ __forceinline__ float sigmoidf_(float x) {
    return fast_rcp(1.0f + fast_exp(-x));
}
__device__ __forceinline__ float tanh_fast(float x) {
    return 1.0f - 2.0f * fast_rcp(1.0f + fast_exp(2.0f * x));
}

// ---------------------------------------------------------------------------
// Kernel 1: pre-project the embedding table through the input kernels (fp32).
// ---------------------------------------------------------------------------
__global__ __launch_bounds__(192) void proj_kernel(
    const float* __restrict__ emb,
    const float* __restrict__ Wf, const float* __restrict__ bif,
    const float* __restrict__ Wb, const float* __restrict__ bib,
    float* __restrict__ proj)            // [2][V][192]
{
    const int dir = blockIdx.y;
    const float* W  = dir ? Wb  : Wf;
    const float* bi = dir ? bib : bif;
    const int v0 = blockIdx.x * VCHUNK;
    const int j  = threadIdx.x;
    const int nrows = min(VCHUNK, V_ - v0);

    __shared__ __align__(16) float s_e[VCHUNK * E_];
    for (int i = j; i < nrows * E_; i += 192) s_e[i] = emb[(size_t)v0 * E_ + i];

    float wcol[E_];
    #pragma unroll
    for (int e = 0; e < E_; ++e) wcol[e] = W[e * G3 + j];
    const float bij = bi[j];
    __syncthreads();

    for (int r = 0; r < nrows; ++r) {
        const float4* x4 = (const float4*)(s_e + r * E_);
        float a0 = 0.f, a1 = 0.f, a2 = 0.f, a3 = 0.f;
        #pragma unroll
        for (int e4 = 0; e4 < 16; e4 += 4) {
            float4 h0 = x4[e4], h1 = x4[e4+1], h2 = x4[e4+2], h3 = x4[e4+3];
            a0 = fmaf(h0.x, wcol[4*e4+ 0], a0); a0 = fmaf(h0.y, wcol[4*e4+ 1], a0);
            a0 = fmaf(h0.z, wcol[4*e4+ 2], a0); a0 = fmaf(h0.w, wcol[4*e4+ 3], a0);
            a1 = fmaf(h1.x, wcol[4*e4+ 4], a1); a1 = fmaf(h1.y, wcol[4*e4+ 5], a1);
            a1 = fmaf(h1.z, wcol[4*e4+ 6], a1); a1 = fmaf(h1.w, wcol[4*e4+ 7], a1);
            a2 = fmaf(h2.x, wcol[4*e4+ 8], a2); a2 = fmaf(h2.y, wcol[4*e4+ 9], a2);
            a2 = fmaf(h2.z, wcol[4*e4+10], a2); a2 = fmaf(h2.w, wcol[4*e4+11], a2);
            a3 = fmaf(h3.x, wcol[4*e4+12], a3); a3 = fmaf(h3.y, wcol[4*e4+13], a3);
            a3 = fmaf(h3.z, wcol[4*e4+14], a3); a3 = fmaf(h3.w, wcol[4*e4+15], a3);
        }
        proj[((size_t)dir * V_ + v0 + r) * G3 + j] = ((a0 + a1) + (a2 + a3)) + bij;
    }
}

// Kernel 2: transpose recurrent kernels (f32): Ut[dir][col][e] = U_dir[e][col]
__global__ void utrans_kernel(const float* __restrict__ Uf,
                              const float* __restrict__ Ub,
                              float* __restrict__ Ut)   // [2][192][64]
{
    const int dir = blockIdx.x;
    const float* U = dir ? Ub : Uf;
    float* o = Ut + (size_t)dir * G3 * H_;
    for (int k = threadIdx.x; k < G3 * H_; k += blockDim.x) {
        const int j = k / H_, e = k % H_;
        o[k] = U[e * G3 + j];
    }
}

// ---------------------------------------------------------------------------
// Kernel 3: the scan. ONE WAVE per (batch row, direction). Lane u owns unit
// u. All math pure f32 — NO f16 conversions (the ~256 in-loop cvts were
// ~half the R10 980-cyc step; they existed only because f16-packed weights
// were the sole way under the ~132-VGPR allocator ceiling). Instead:
//   z-columns: 64 f32 in pinned VGPRs (proven resident at this count)
//   r,c-columns: staged once into LDS (32KB, row stride 68 f32 so per-lane
//     b128 reads spread across banks -> 8-cyc BW bound, not bank-0 pileup)
//   h: f32 in one 256-B LDS row (16 broadcast b128 reads)
// Per step: 192 scalar v_fma (384 issue cyc) overlapping ~50 DS ops on the
// separate DS pipe. xw from an 8-step LDS chunk (vm wait once per chunk).
// Outputs stored directly, coalesced, never waited on. No barriers/shuffles.
// ---------------------------------------------------------------------------
__global__ __launch_bounds__(64, 1)
void gru_scan16(
    const int*   __restrict__ inputs,   // [B,S]
    const float* __restrict__ proj,     // [2][V][192]
    const float* __restrict__ Ut,       // [2][192][64] f32
    const float* __restrict__ brf, const float* __restrict__ brb,
    float* __restrict__ gru_out)        // [B,S,2H]
{
    const int b   = blockIdx.x >> 1;
    const int dir = blockIdx.x & 1;
    const int u   = threadIdx.x;           // == unit

    const float* eproj = proj + (size_t)dir * V_ * G3;
    const float* br    = dir ? brb : brf;

    __shared__ __align__(16) int   s_tok[STOK];          // scan order + pad
    __shared__ __align__(16) float s_h[H_];              // f32 h row
    __shared__ __align__(16) float s_w[128][WPAD];       // r(0..63),c(64..127)
    __shared__ __align__(16) float s_xw[2][CHUNK * G3];  // 2 x 6 KB

    for (int t = u; t < S_; t += 64)
        s_tok[t] = inputs[b * S_ + (dir ? (S_ - 1 - t) : t)];
    for (int t = S_ + u; t < STOK; t += 64) s_tok[t] = 0;  // pad -> row 0
    s_h[u] = 0.0f;

    // stage r,c weight columns into LDS (one-time, coalesced)
    {
        const float* src = Ut + ((size_t)dir * G3 + 64) * H_;   // 128 x 64
        for (int idx = u; idx < 128 * H_; idx += 64) {
            const int row = idx >> 6, e = idx & 63;
            s_w[row][e] = src[idx];
        }
    }

    // z-columns in registers: 16 f32x4 = 64 VGPRs, pinned.
    f32x4 wz[16];
    {
        const f32x4* p = (const f32x4*)(Ut + ((size_t)dir * G3 + u) * H_);
        #pragma unroll
        for (int k = 0; k < 16; ++k) wz[k] = p[k];
        #pragma unroll
        for (int k = 0; k < 16; ++k) asm volatile("" : "+v"(wz[k]));
    }
    const float br0 = br[u], br1 = br[u + 64], br2 = br[u + 128];
    float res = 0.0f;                      // lane u's h value

    // ---- chunk staging: 6 f32x4 per lane = one 8-step chunk ----------
    f32x4 ld[6];
    auto stage_issue = [&](int baseStep) {
        #pragma unroll
        for (int i = 0; i < 6; ++i) {
            const int idx = i * 64 + u;      // 16B slot (0..383)
            const int row = idx / 48;        // 48 slots per 192-float row
            const int off = idx - row * 48;
            const int tk  = s_tok[baseStep + row];
            ld[i] = *(const f32x4*)(eproj + (size_t)tk * G3 + off * 4);
        }
    };
    auto stage_write = [&](int nbuf) {
        #pragma unroll
        for (int i = 0; i < 6; ++i) {
            const int idx = i * 64 + u;
            *(f32x4*)(&s_xw[nbuf][idx * 4]) = ld[i];
        }
    };

    stage_issue(0);
    stage_write(0);
    __builtin_amdgcn_wave_barrier();

    const float* wrp = &s_w[u][0];          // lane's r column
    const float* wcp = &s_w[64 + u][0];     // lane's c column
    float* outb = gru_out + (size_t)b * S_ * (2 * H_) + dir * H_ + u;

    for (int c = 0; c < NCHUNK; ++c) {
        const int buf = c & 1;
        stage_issue((c + 1) * CHUNK);        // next chunk loads (pad-safe)

        #pragma unroll 1
        for (int t0 = 0; t0 < CHUNK; ++t0) {
            const int t = c * CHUNK + t0;

            const int   tok = s_tok[t];                       // broadcast b32
            const float x0  = s_xw[buf][t0 * G3 + u];
            const float x1  = s_xw[buf][t0 * G3 + u + 64];
            const float x2  = s_xw[buf][t0 * G3 + u + 128];

            // three 64-dots, pure f32: z from regs, r/c streamed from LDS
            const f32x4* h4 = (const f32x4*)s_h;
            float z0 = br0, z1 = 0.f;
            float r0 = br1, r1 = 0.f;
            float c0 = br2, c1 = 0.f;
            #pragma unroll
            for (int k = 0; k < 16; ++k) {
                const f32x4 hq = h4[k];                        // broadcast
                const f32x4 rq = *(const f32x4*)(wrp + 4 * k); // per-lane
                const f32x4 cq = *(const f32x4*)(wcp + 4 * k); // per-lane
                const f32x4 zq = wz[k];
                z0 = fmaf(hq.x, zq.x, z0); z1 = fmaf(hq.y, zq.y, z1);
                z0 = fmaf(hq.z, zq.z, z0); z1 = fmaf(hq.w, zq.w, z1);
                r0 = fmaf(hq.x, rq.x, r0); r1 = fmaf(hq.y, rq.y, r1);
                r0 = fmaf(hq.z, rq.z, r0); r1 = fmaf(hq.w, rq.w, r1);
                c0 = fmaf(hq.x, cq.x, c0); c1 = fmaf(hq.y, cq.y, c1);
                c0 = fmaf(hq.z, cq.z, c0); c1 = fmaf(hq.w, cq.w, c1);
            }
            const float d0 = z0 + z1;
            const float d1 = r0 + r1;
            const float d2 = c0 + c1;

            const float z    = sigmoidf_(x0 + d0);
            const float r    = sigmoidf_(x1 + d1);
            const float hh   = tanh_fast(fmaf(r, d2, x2));
            const float hn   = fmaf(z, res - hh, hh);
            res = (tok != 0) ? hn : res;               // mask_zero carry

            s_h[u] = res;
            __builtin_amdgcn_wave_barrier();   // write ordered before reads

            const int tt = dir ? (S_ - 1 - t) : t;
            outb[(size_t)tt * (2 * H_)] = res;         // coalesced, no wait
        }

        stage_write(buf ^ 1);   // vm wait once per 8 steps
        __builtin_amdgcn_wave_barrier();
    }
}

// x1 = sigmoid(gru_out @ w1 + b1), x2 = sigmoid(gru_out @ w2 + b2)
__global__ __launch_bounds__(256) void head_kernel(
    const float* __restrict__ gru,      // [B*S, 2H]
    const float* __restrict__ w1, const float* __restrict__ b1,
    const float* __restrict__ w2, const float* __restrict__ b2,
    float* __restrict__ x1, float* __restrict__ x2)
{
    __shared__ __align__(16) float s_w1[2 * H_];
    __shared__ __align__(16) float s_w2[2 * H_];
    const int tid = threadIdx.x;
    if (tid < 2 * H_)      s_w1[tid]          = w1[tid];
    else                   s_w2[tid - 2 * H_] = w2[tid - 2 * H_];
    __syncthreads();

    const int i = blockIdx.x * 256 + tid;
    const float4* g4 = (const float4*)(gru + (size_t)i * (2 * H_));
    float a1 = b1[0], a2 = b2[0];
    #pragma unroll
    for (int k = 0; k < (2 * H_) / 4; ++k) {
        const float4 v  = g4[k];
        const float4 q1 = ((const float4*)s_w1)[k];
        const float4 q2 = ((const float4*)s_w2)[k];
        a1 += v.x * q1.x + v.y * q1.y + v.z * q1.z + v.w * q1.w;
        a2 += v.x * q2.x + v.y * q2.y + v.z * q2.z + v.w * q2.w;
    }
    x1[i] = 1.0f / (1.0f + __expf(-a1));
    x2[i] = 1.0f / (1.0f + __expf(-a2));
}

extern "C" void kernel_launch(void* const* d_in, const int* in_sizes, int n_in,
                              void* d_out, int out_size, void* d_ws, size_t ws_size,
                              hipStream_t stream) {
    (void)in_sizes; (void)n_in; (void)ws_size; (void)out_size;

    const int*   inputs = (const int*)  d_in[0];
    const float* emb    = (const float*)d_in[1];
    const float* Wf     = (const float*)d_in[2];
    const float* Uf     = (const float*)d_in[3];
    const float* bif    = (const float*)d_in[4];
    const float* brf    = (const float*)d_in[5];
    const float* Wb     = (const float*)d_in[6];
    const float* Ub     = (const float*)d_in[7];
    const float* bib    = (const float*)d_in[8];
    const float* brb    = (const float*)d_in[9];
    const float* w1     = (const float*)d_in[10];
    const float* b1     = (const float*)d_in[11];
    const float* w2     = (const float*)d_in[12];
    const float* b2     = (const float*)d_in[13];

    float* out = (float*)d_out;
    float* x1  = out;                       // [B*S]
    float* x2  = out + (size_t)B_ * S_;     // [B*S]
    float* gru = out + (size_t)2 * B_ * S_; // [B*S, 2H]

    // workspace: proj [2][V][192] f32 (7.67 MB), then Ut [2][192][64] f32 (96 KB)
    float* proj = (float*)d_ws;
    float* Ut   = proj + (size_t)2 * V_ * G3;

    proj_kernel<<<dim3((V_ + VCHUNK - 1) / VCHUNK, 2), 192, 0, stream>>>(
        emb, Wf, bif, Wb, bib, proj);
    utrans_kernel<<<2, 256, 0, stream>>>(Uf, Ub, Ut);

    gru_scan16<<<B_ * 2, 64, 0, stream>>>(inputs, proj, Ut, brf, brb, gru);

    head_kernel<<<(B_ * S_) / 256, 256, 0, stream>>>(gru, w1, b1, w2, b2, x1, x2);
}